// Round 4
// baseline (175.384 us; speedup 1.0000x reference)
//
#include <hip/hip_runtime.h>

#define BATCH 16
#define NX 1024
#define NY 1024
#define CHUNK 8
#define PLANE (NX * NY)

// Each thread owns 4 consecutive y values (y0..y0+3); a 256-thread block
// covers the full y-extent of one row. Threads march x across a CHUNK,
// carrying per-row derived quantities in registers (sliding window m/c/p).
struct Row4 {
    float fc[4];   // f
    float pa[4];   // A0*f
    float rr[4];   // B0*f
    float dq[4];   // Dy(A1*f)
    float d2s[4];  // Dyy(B1*f)
    float dtT[4];  // Dy(B2*f)
};

__device__ __forceinline__ Row4 make_row4(
    int xx, int y0, int tid,
    const float* __restrict__ fb, const float* __restrict__ A0,
    const float* __restrict__ A1, const float* __restrict__ B0,
    const float* __restrict__ B1, const float* __restrict__ B2)
{
    const int base = xx * NY + y0;
    const bool has_l = (tid > 0);
    const bool has_r = (tid < 255);

    // f: center float4 + halo scalars
    const float4 f4 = *(const float4*)(fb + base);
    const float fl = has_l ? fb[base - 1] : 0.0f;
    const float fr = has_r ? fb[base + 4] : 0.0f;

    const float4 a0 = *(const float4*)(A0 + base);
    const float4 b0 = *(const float4*)(B0 + base);

    const float4 a1 = *(const float4*)(A1 + base);
    const float a1l = has_l ? A1[base - 1] : 0.0f;
    const float a1r = has_r ? A1[base + 4] : 0.0f;

    const float4 b1 = *(const float4*)(B1 + base);
    const float b1l = has_l ? B1[base - 1] : 0.0f;
    const float b1r = has_r ? B1[base + 4] : 0.0f;

    const float4 b2 = *(const float4*)(B2 + base);
    const float b2l = has_l ? B2[base - 1] : 0.0f;
    const float b2r = has_r ? B2[base + 4] : 0.0f;

    // extended products over y0-1 .. y0+4
    float fe[6] = { fl, f4.x, f4.y, f4.z, f4.w, fr };
    float qe[6] = { a1l * fl, a1.x * f4.x, a1.y * f4.y, a1.z * f4.z, a1.w * f4.w, a1r * fr };
    float se[6] = { b1l * fl, b1.x * f4.x, b1.y * f4.y, b1.z * f4.z, b1.w * f4.w, b1r * fr };
    float te[6] = { b2l * fl, b2.x * f4.x, b2.y * f4.y, b2.z * f4.z, b2.w * f4.w, b2r * fr };

    Row4 r;
    r.fc[0] = fe[1]; r.fc[1] = fe[2]; r.fc[2] = fe[3]; r.fc[3] = fe[4];
    r.pa[0] = a0.x * f4.x; r.pa[1] = a0.y * f4.y; r.pa[2] = a0.z * f4.z; r.pa[3] = a0.w * f4.w;
    r.rr[0] = b0.x * f4.x; r.rr[1] = b0.y * f4.y; r.rr[2] = b0.z * f4.z; r.rr[3] = b0.w * f4.w;

    #pragma unroll
    for (int i = 0; i < 4; ++i) {
        r.dq[i]  = 0.5f * (qe[i + 2] - qe[i]);
        r.d2s[i] = se[i + 2] - 2.0f * se[i + 1] + se[i];
        r.dtT[i] = 0.5f * (te[i + 2] - te[i]);
    }
    // y = 0 one-sided (element 0 of tid 0)
    if (tid == 0) {
        r.dq[0]  = 0.5f * (-3.0f * qe[1] + 4.0f * qe[2] - qe[3]);
        r.d2s[0] = 2.0f * se[1] - 5.0f * se[2] + 4.0f * se[3] - se[4];
        r.dtT[0] = 0.5f * (-3.0f * te[1] + 4.0f * te[2] - te[3]);
    }
    // y = NY-1 one-sided (element 3 of tid 255)
    if (tid == 255) {
        r.dq[3]  = 0.5f * (3.0f * qe[4] - 4.0f * qe[3] + qe[2]);
        r.d2s[3] = 2.0f * se[4] - 5.0f * se[3] + 4.0f * se[2] - se[1];
        r.dtT[3] = 0.5f * (3.0f * te[4] - 4.0f * te[3] + te[2]);
    }
    return r;
}

__global__ __launch_bounds__(256) void fp2d_kernel(
    const float* __restrict__ f,
    const float* __restrict__ Ag,
    const float* __restrict__ Bg,
    const float* __restrict__ dt,
    float* __restrict__ out)
{
    const int tid = threadIdx.x;
    const int y0  = tid * 4;
    const int x0  = blockIdx.x * CHUNK;   // xc fastest -> XCD gets xc = k mod 8 (L2 grid reuse)
    const int b   = blockIdx.y;

    const float* __restrict__ fb = f + (size_t)b * PLANE;
    float* __restrict__ ob = out + (size_t)b * PLANE;
    const float dtb = dt[b];
    const float* __restrict__ A0 = Ag;
    const float* __restrict__ A1 = Ag + PLANE;
    const float* __restrict__ B0 = Bg;
    const float* __restrict__ B1 = Bg + PLANE;
    const float* __restrict__ B2 = Bg + 2 * PLANE;

    int cs = x0;
    int ce = x0 + CHUNK - 1;
    if (cs == 0) cs = 1;
    if (ce == NX - 1) ce = NX - 2;

    Row4 m = make_row4(cs - 1, y0, tid, fb, A0, A1, B0, B1, B2);
    Row4 c = make_row4(cs,     y0, tid, fb, A0, A1, B0, B1, B2);
    #pragma unroll 2
    for (int x = cs; x <= ce; ++x) {
        Row4 p = make_row4(x + 1, y0, tid, fb, A0, A1, B0, B1, B2);
        float4 o;
        float* op = &o.x;
        #pragma unroll
        for (int i = 0; i < 4; ++i) {
            const float dxP   = 0.5f * (p.pa[i] - m.pa[i]);
            const float dxxR  = p.rr[i] - 2.0f * c.rr[i] + m.rr[i];
            const float dxdyT = 0.5f * (p.dtT[i] - m.dtT[i]);
            const float df = -(dxP + c.dq[i]) + 0.5f * (dxxR + c.d2s[i]) + dxdyT;
            op[i] = fmaxf(c.fc[i] + df * dtb, 0.0f);
        }
        *(float4*)(ob + x * NY + y0) = o;
        m = c; c = p;
    }

    // x = 0 one-sided (only first chunk; block-uniform branch)
    if (x0 == 0) {
        Row4 r0 = make_row4(0, y0, tid, fb, A0, A1, B0, B1, B2);
        Row4 r1 = make_row4(1, y0, tid, fb, A0, A1, B0, B1, B2);
        Row4 r2 = make_row4(2, y0, tid, fb, A0, A1, B0, B1, B2);
        Row4 r3 = make_row4(3, y0, tid, fb, A0, A1, B0, B1, B2);
        float4 o; float* op = &o.x;
        #pragma unroll
        for (int i = 0; i < 4; ++i) {
            const float dxP   = 0.5f * (-3.0f * r0.pa[i] + 4.0f * r1.pa[i] - r2.pa[i]);
            const float dxxR  = 2.0f * r0.rr[i] - 5.0f * r1.rr[i] + 4.0f * r2.rr[i] - r3.rr[i];
            const float dxdyT = 0.5f * (-3.0f * r0.dtT[i] + 4.0f * r1.dtT[i] - r2.dtT[i]);
            const float df = -(dxP + r0.dq[i]) + 0.5f * (dxxR + r0.d2s[i]) + dxdyT;
            op[i] = fmaxf(r0.fc[i] + df * dtb, 0.0f);
        }
        *(float4*)(ob + y0) = o;
    }

    // x = NX-1 one-sided (only last chunk)
    if (x0 + CHUNK == NX) {
        Row4 r0 = make_row4(NX - 1, y0, tid, fb, A0, A1, B0, B1, B2);
        Row4 r1 = make_row4(NX - 2, y0, tid, fb, A0, A1, B0, B1, B2);
        Row4 r2 = make_row4(NX - 3, y0, tid, fb, A0, A1, B0, B1, B2);
        Row4 r3 = make_row4(NX - 4, y0, tid, fb, A0, A1, B0, B1, B2);
        float4 o; float* op = &o.x;
        #pragma unroll
        for (int i = 0; i < 4; ++i) {
            const float dxP   = 0.5f * (3.0f * r0.pa[i] - 4.0f * r1.pa[i] + r2.pa[i]);
            const float dxxR  = 2.0f * r0.rr[i] - 5.0f * r1.rr[i] + 4.0f * r2.rr[i] - r3.rr[i];
            const float dxdyT = 0.5f * (3.0f * r0.dtT[i] - 4.0f * r1.dtT[i] + r2.dtT[i]);
            const float df = -(dxP + r0.dq[i]) + 0.5f * (dxxR + r0.d2s[i]) + dxdyT;
            op[i] = fmaxf(r0.fc[i] + df * dtb, 0.0f);
        }
        *(float4*)(ob + (NX - 1) * NY + y0) = o;
    }
}

extern "C" void kernel_launch(void* const* d_in, const int* in_sizes, int n_in,
                              void* d_out, int out_size, void* d_ws, size_t ws_size,
                              hipStream_t stream) {
    const float* f  = (const float*)d_in[0];
    const float* Ag = (const float*)d_in[1];
    const float* Bg = (const float*)d_in[2];
    const float* dt = (const float*)d_in[3];
    float* out = (float*)d_out;

    dim3 block(256, 1, 1);
    dim3 grid(NX / CHUNK, BATCH, 1);
    fp2d_kernel<<<grid, block, 0, stream>>>(f, Ag, Bg, dt, out);
}

// Round 6
// 161.710 us; speedup vs baseline: 1.0846x; 1.0846x over previous
//
#include <hip/hip_runtime.h>

#define BATCH 16
#define NX 1024
#define NY 1024
#define CHUNK 16
#define PLANE (NX * NY)

typedef float v4f __attribute__((ext_vector_type(4)));

// Each thread owns 4 consecutive y (y0..y0+3); a 256-thread block covers the
// full y row. Threads march x over a CHUNK carrying a 3-row sliding window.
// y-halos come from neighbor lanes via __shfl (products q=A1*f, s=B1*f,
// t=B2*f), not from extra global loads; wave-edge lanes load the halo
// scalars exec-masked (1 active lane per wave boundary).

struct Raw {
    v4f f, a0, a1, b0, b1, b2;
    float fl, a1l, b1l, b2l;   // left halo (only valid on wave-edge lanes)
    float fr, a1r, b1r, b2r;   // right halo
};

struct Row4 { float fc[4], pa[4], rr[4], dq[4], d2s[4], dtT[4]; };

__device__ __forceinline__ Raw load_raw(int xx, int y0, int tid,
    const float* __restrict__ fb, const float* __restrict__ A0,
    const float* __restrict__ A1, const float* __restrict__ B0,
    const float* __restrict__ B1, const float* __restrict__ B2)
{
    const int base = xx * NY + y0;
    Raw r;
    r.f  = *(const v4f*)(fb + base);
    r.a0 = *(const v4f*)(A0 + base);
    r.a1 = *(const v4f*)(A1 + base);
    r.b0 = *(const v4f*)(B0 + base);
    r.b1 = *(const v4f*)(B1 + base);
    r.b2 = *(const v4f*)(B2 + base);

    const int lane = tid & 63;
    const bool nl = (lane == 0)  && (tid > 0);    // cross-wave left halo
    const bool nr = (lane == 63) && (tid < 255);  // cross-wave right halo
    r.fl  = nl ? fb[base - 1] : 0.0f;
    r.a1l = nl ? A1[base - 1] : 0.0f;
    r.b1l = nl ? B1[base - 1] : 0.0f;
    r.b2l = nl ? B2[base - 1] : 0.0f;
    r.fr  = nr ? fb[base + 4] : 0.0f;
    r.a1r = nr ? A1[base + 4] : 0.0f;
    r.b1r = nr ? B1[base + 4] : 0.0f;
    r.b2r = nr ? B2[base + 4] : 0.0f;
    return r;
}

__device__ __forceinline__ Row4 convert(const Raw& r, int tid)
{
    const int lane = tid & 63;

    const float q0 = r.a1.x * r.f.x, q1 = r.a1.y * r.f.y,
                q2 = r.a1.z * r.f.z, q3 = r.a1.w * r.f.w;
    const float s0 = r.b1.x * r.f.x, s1 = r.b1.y * r.f.y,
                s2 = r.b1.z * r.f.z, s3 = r.b1.w * r.f.w;
    const float t0 = r.b2.x * r.f.x, t1 = r.b2.y * r.f.y,
                t2 = r.b2.z * r.f.z, t3 = r.b2.w * r.f.w;

    // neighbor-lane halos (in-wave via shuffle, wave-edge via masked loads)
    float qm = __shfl_up(q3, 1), sm = __shfl_up(s3, 1), tm = __shfl_up(t3, 1);
    float qp = __shfl_down(q0, 1), sp = __shfl_down(s0, 1), tp = __shfl_down(t0, 1);
    if (lane == 0)  { qm = r.a1l * r.fl; sm = r.b1l * r.fl; tm = r.b2l * r.fl; }
    if (lane == 63) { qp = r.a1r * r.fr; sp = r.b1r * r.fr; tp = r.b2r * r.fr; }

    const float qe[6] = { qm, q0, q1, q2, q3, qp };
    const float se[6] = { sm, s0, s1, s2, s3, sp };
    const float te[6] = { tm, t0, t1, t2, t3, tp };

    Row4 o;
    o.fc[0] = r.f.x; o.fc[1] = r.f.y; o.fc[2] = r.f.z; o.fc[3] = r.f.w;
    o.pa[0] = r.a0.x * r.f.x; o.pa[1] = r.a0.y * r.f.y;
    o.pa[2] = r.a0.z * r.f.z; o.pa[3] = r.a0.w * r.f.w;
    o.rr[0] = r.b0.x * r.f.x; o.rr[1] = r.b0.y * r.f.y;
    o.rr[2] = r.b0.z * r.f.z; o.rr[3] = r.b0.w * r.f.w;

    #pragma unroll
    for (int i = 0; i < 4; ++i) {
        o.dq[i]  = 0.5f * (qe[i + 2] - qe[i]);
        o.d2s[i] = se[i + 2] - 2.0f * se[i + 1] + se[i];
        o.dtT[i] = 0.5f * (te[i + 2] - te[i]);
    }
    if (tid == 0) { // y = 0 one-sided
        o.dq[0]  = 0.5f * (-3.0f * qe[1] + 4.0f * qe[2] - qe[3]);
        o.d2s[0] = 2.0f * se[1] - 5.0f * se[2] + 4.0f * se[3] - se[4];
        o.dtT[0] = 0.5f * (-3.0f * te[1] + 4.0f * te[2] - te[3]);
    }
    if (tid == 255) { // y = NY-1 one-sided
        o.dq[3]  = 0.5f * (3.0f * qe[4] - 4.0f * qe[3] + qe[2]);
        o.d2s[3] = 2.0f * se[4] - 5.0f * se[3] + 4.0f * se[2] - se[1];
        o.dtT[3] = 0.5f * (3.0f * te[4] - 4.0f * te[3] + te[2]);
    }
    return o;
}

__global__ __launch_bounds__(256) void fp2d_kernel(
    const float* __restrict__ f,
    const float* __restrict__ Ag,
    const float* __restrict__ Bg,
    const float* __restrict__ dt,
    float* __restrict__ out)
{
    const int tid = threadIdx.x;
    const int y0  = tid * 4;
    const int x0  = blockIdx.x * CHUNK;   // xc fastest -> XCD-local grid reuse
    const int b   = blockIdx.y;

    const float* __restrict__ fb = f + (size_t)b * PLANE;
    float* __restrict__ ob = out + (size_t)b * PLANE;
    const float dtb = dt[b];
    const float* __restrict__ A0 = Ag;
    const float* __restrict__ A1 = Ag + PLANE;
    const float* __restrict__ B0 = Bg;
    const float* __restrict__ B1 = Bg + PLANE;
    const float* __restrict__ B2 = Bg + 2 * PLANE;

    const int cs = (x0 == 0) ? 1 : x0;
    const int ce = (x0 + CHUNK == NX) ? NX - 2 : x0 + CHUNK - 1;

    Row4 m = convert(load_raw(cs - 1, y0, tid, fb, A0, A1, B0, B1, B2), tid);
    Row4 c = convert(load_raw(cs,     y0, tid, fb, A0, A1, B0, B1, B2), tid);
    Raw rp = load_raw(cs + 1, y0, tid, fb, A0, A1, B0, B1, B2);

    #pragma unroll 2
    for (int x = cs; x <= ce; ++x) {
        const int xn = (x + 2 < NX) ? x + 2 : NX - 1;
        Raw rn = load_raw(xn, y0, tid, fb, A0, A1, B0, B1, B2); // prefetch
        Row4 p = convert(rp, tid);
        v4f o;
        #pragma unroll
        for (int i = 0; i < 4; ++i) {
            const float dxP   = 0.5f * (p.pa[i] - m.pa[i]);
            const float dxxR  = p.rr[i] - 2.0f * c.rr[i] + m.rr[i];
            const float dxdyT = 0.5f * (p.dtT[i] - m.dtT[i]);
            const float df = -(dxP + c.dq[i]) + 0.5f * (dxxR + c.d2s[i]) + dxdyT;
            o[i] = fmaxf(c.fc[i] + df * dtb, 0.0f);
        }
        __builtin_nontemporal_store(o, (v4f*)(ob + x * NY + y0));
        m = c; c = p; rp = rn;
    }

    // x = 0 one-sided (first chunk only; block-uniform branch)
    if (x0 == 0) {
        Row4 r0 = convert(load_raw(0, y0, tid, fb, A0, A1, B0, B1, B2), tid);
        Row4 r1 = convert(load_raw(1, y0, tid, fb, A0, A1, B0, B1, B2), tid);
        Row4 r2 = convert(load_raw(2, y0, tid, fb, A0, A1, B0, B1, B2), tid);
        Row4 r3 = convert(load_raw(3, y0, tid, fb, A0, A1, B0, B1, B2), tid);
        v4f o;
        #pragma unroll
        for (int i = 0; i < 4; ++i) {
            const float dxP   = 0.5f * (-3.0f * r0.pa[i] + 4.0f * r1.pa[i] - r2.pa[i]);
            const float dxxR  = 2.0f * r0.rr[i] - 5.0f * r1.rr[i] + 4.0f * r2.rr[i] - r3.rr[i];
            const float dxdyT = 0.5f * (-3.0f * r0.dtT[i] + 4.0f * r1.dtT[i] - r2.dtT[i]);
            const float df = -(dxP + r0.dq[i]) + 0.5f * (dxxR + r0.d2s[i]) + dxdyT;
            o[i] = fmaxf(r0.fc[i] + df * dtb, 0.0f);
        }
        __builtin_nontemporal_store(o, (v4f*)(ob + y0));
    }

    // x = NX-1 one-sided (last chunk only)
    if (x0 + CHUNK == NX) {
        Row4 r0 = convert(load_raw(NX - 1, y0, tid, fb, A0, A1, B0, B1, B2), tid);
        Row4 r1 = convert(load_raw(NX - 2, y0, tid, fb, A0, A1, B0, B1, B2), tid);
        Row4 r2 = convert(load_raw(NX - 3, y0, tid, fb, A0, A1, B0, B1, B2), tid);
        Row4 r3 = convert(load_raw(NX - 4, y0, tid, fb, A0, A1, B0, B1, B2), tid);
        v4f o;
        #pragma unroll
        for (int i = 0; i < 4; ++i) {
            const float dxP   = 0.5f * (3.0f * r0.pa[i] - 4.0f * r1.pa[i] + r2.pa[i]);
            const float dxxR  = 2.0f * r0.rr[i] - 5.0f * r1.rr[i] + 4.0f * r2.rr[i] - r3.rr[i];
            const float dxdyT = 0.5f * (3.0f * r0.dtT[i] - 4.0f * r1.dtT[i] + r2.dtT[i]);
            const float df = -(dxP + r0.dq[i]) + 0.5f * (dxxR + r0.d2s[i]) + dxdyT;
            o[i] = fmaxf(r0.fc[i] + df * dtb, 0.0f);
        }
        __builtin_nontemporal_store(o, (v4f*)(ob + (NX - 1) * NY + y0));
    }
}

extern "C" void kernel_launch(void* const* d_in, const int* in_sizes, int n_in,
                              void* d_out, int out_size, void* d_ws, size_t ws_size,
                              hipStream_t stream) {
    const float* f  = (const float*)d_in[0];
    const float* Ag = (const float*)d_in[1];
    const float* Bg = (const float*)d_in[2];
    const float* dt = (const float*)d_in[3];
    float* out = (float*)d_out;

    dim3 block(256, 1, 1);
    dim3 grid(NX / CHUNK, BATCH, 1);
    fp2d_kernel<<<grid, block, 0, stream>>>(f, Ag, Bg, dt, out);
}

// Round 7
// 148.135 us; speedup vs baseline: 1.1839x; 1.0916x over previous
//
#include <hip/hip_runtime.h>

#define BATCH 16
#define NX 1024
#define NY 1024
#define CHUNK 8
#define NB 2              // batches per block: grid arrays loaded once, reused NB times
#define PLANE (NX * NY)

typedef float v4f __attribute__((ext_vector_type(4)));

// Shared (batch-independent) per-row raw data
struct RawS { v4f a0, a1, b0, b1, b2; float a1l, b1l, b2l, a1r, b1r, b2r; };
// Per-batch per-row raw data
struct RawF { v4f f; float fl, fr; };
// Shared shuffled y-halo grid values
struct Halo { float a1m, b1m, b2m, a1p, b1p, b2p; };
// Per-batch converted row state.  yc = -dq + 0.5*d2s (combined y-contribution)
struct Row  { float pa[4], rr[4], tt[4], fc[4], yc[4]; };

__device__ __forceinline__ RawS load_rawS(int xx, int y0, int tid,
    const float* __restrict__ A0, const float* __restrict__ A1,
    const float* __restrict__ B0, const float* __restrict__ B1,
    const float* __restrict__ B2)
{
    const int base = xx * NY + y0;
    RawS r;
    r.a0 = *(const v4f*)(A0 + base);
    r.a1 = *(const v4f*)(A1 + base);
    r.b0 = *(const v4f*)(B0 + base);
    r.b1 = *(const v4f*)(B1 + base);
    r.b2 = *(const v4f*)(B2 + base);
    const int lane = tid & 63;
    const bool nl = (lane == 0)  && (tid > 0);    // cross-wave left halo
    const bool nr = (lane == 63) && (tid < 255);  // cross-wave right halo
    r.a1l = nl ? A1[base - 1] : 0.0f;
    r.b1l = nl ? B1[base - 1] : 0.0f;
    r.b2l = nl ? B2[base - 1] : 0.0f;
    r.a1r = nr ? A1[base + 4] : 0.0f;
    r.b1r = nr ? B1[base + 4] : 0.0f;
    r.b2r = nr ? B2[base + 4] : 0.0f;
    return r;
}

__device__ __forceinline__ RawF load_rawF(int xx, int y0, int tid,
    const float* __restrict__ fb)
{
    const int base = xx * NY + y0;
    RawF r;
    r.f = *(const v4f*)(fb + base);
    const int lane = tid & 63;
    const bool nl = (lane == 0)  && (tid > 0);
    const bool nr = (lane == 63) && (tid < 255);
    r.fl = nl ? fb[base - 1] : 0.0f;
    r.fr = nr ? fb[base + 4] : 0.0f;
    return r;
}

__device__ __forceinline__ Halo make_halo(const RawS& rs, int tid)
{
    const int lane = tid & 63;
    Halo h;
    h.a1m = __shfl_up(rs.a1.w, 1);   h.b1m = __shfl_up(rs.b1.w, 1);
    h.b2m = __shfl_up(rs.b2.w, 1);
    h.a1p = __shfl_down(rs.a1.x, 1); h.b1p = __shfl_down(rs.b1.x, 1);
    h.b2p = __shfl_down(rs.b2.x, 1);
    if (lane == 0)  { h.a1m = rs.a1l; h.b1m = rs.b1l; h.b2m = rs.b2l; }
    if (lane == 63) { h.a1p = rs.a1r; h.b1p = rs.b1r; h.b2p = rs.b2r; }
    return h;
}

__device__ __forceinline__ Row convert(const RawS& rs, const Halo& h,
                                       const RawF& rf, int tid)
{
    const int lane = tid & 63;
    float fm = __shfl_up(rf.f.w, 1);
    float fp = __shfl_down(rf.f.x, 1);
    if (lane == 0)  fm = rf.fl;
    if (lane == 63) fp = rf.fr;

    const float qe[6] = { h.a1m * fm, rs.a1.x * rf.f.x, rs.a1.y * rf.f.y,
                          rs.a1.z * rf.f.z, rs.a1.w * rf.f.w, h.a1p * fp };
    const float se[6] = { h.b1m * fm, rs.b1.x * rf.f.x, rs.b1.y * rf.f.y,
                          rs.b1.z * rf.f.z, rs.b1.w * rf.f.w, h.b1p * fp };
    const float te[6] = { h.b2m * fm, rs.b2.x * rf.f.x, rs.b2.y * rf.f.y,
                          rs.b2.z * rf.f.z, rs.b2.w * rf.f.w, h.b2p * fp };

    Row o;
    o.fc[0] = rf.f.x; o.fc[1] = rf.f.y; o.fc[2] = rf.f.z; o.fc[3] = rf.f.w;
    o.pa[0] = rs.a0.x * rf.f.x; o.pa[1] = rs.a0.y * rf.f.y;
    o.pa[2] = rs.a0.z * rf.f.z; o.pa[3] = rs.a0.w * rf.f.w;
    o.rr[0] = rs.b0.x * rf.f.x; o.rr[1] = rs.b0.y * rf.f.y;
    o.rr[2] = rs.b0.z * rf.f.z; o.rr[3] = rs.b0.w * rf.f.w;

    #pragma unroll
    for (int i = 0; i < 4; ++i) {
        const float dq  = 0.5f * (qe[i + 2] - qe[i]);
        const float d2s = se[i + 2] - 2.0f * se[i + 1] + se[i];
        o.tt[i] = 0.5f * (te[i + 2] - te[i]);
        o.yc[i] = -dq + 0.5f * d2s;
    }
    if (tid == 0) { // y = 0 one-sided
        const float dq  = 0.5f * (-3.0f * qe[1] + 4.0f * qe[2] - qe[3]);
        const float d2s = 2.0f * se[1] - 5.0f * se[2] + 4.0f * se[3] - se[4];
        o.tt[0] = 0.5f * (-3.0f * te[1] + 4.0f * te[2] - te[3]);
        o.yc[0] = -dq + 0.5f * d2s;
    }
    if (tid == 255) { // y = NY-1 one-sided
        const float dq  = 0.5f * (3.0f * qe[4] - 4.0f * qe[3] + qe[2]);
        const float d2s = 2.0f * se[4] - 5.0f * se[3] + 4.0f * se[2] - se[1];
        o.tt[3] = 0.5f * (3.0f * te[4] - 4.0f * te[3] + te[2]);
        o.yc[3] = -dq + 0.5f * d2s;
    }
    return o;
}

__global__ __launch_bounds__(256) void fp2d_kernel(
    const float* __restrict__ f,
    const float* __restrict__ Ag,
    const float* __restrict__ Bg,
    const float* __restrict__ dt,
    float* __restrict__ out)
{
    const int tid = threadIdx.x;
    const int y0  = tid * 4;
    const int x0  = blockIdx.x * CHUNK;     // xc fastest -> XCD-local grid reuse
    const int bb  = blockIdx.y * NB;

    const float* __restrict__ A0 = Ag;
    const float* __restrict__ A1 = Ag + PLANE;
    const float* __restrict__ B0 = Bg;
    const float* __restrict__ B1 = Bg + PLANE;
    const float* __restrict__ B2 = Bg + 2 * PLANE;

    const float* fb[NB];
    float* ob[NB];
    float dtb[NB];
    #pragma unroll
    for (int j = 0; j < NB; ++j) {
        fb[j]  = f   + (size_t)(bb + j) * PLANE;
        ob[j]  = out + (size_t)(bb + j) * PLANE;
        dtb[j] = dt[bb + j];
    }

    const int cs = (x0 == 0) ? 1 : x0;
    const int ce = (x0 + CHUNK == NX) ? NX - 2 : x0 + CHUNK - 1;

    // Prologue: rows cs-1 and cs converted; row cs+1 raw (prefetched)
    {
    }
    RawS sM = load_rawS(cs - 1, y0, tid, A0, A1, B0, B1, B2);
    RawS sC = load_rawS(cs,     y0, tid, A0, A1, B0, B1, B2);
    RawS sP = load_rawS(cs + 1, y0, tid, A0, A1, B0, B1, B2);
    RawF fM[NB], fC[NB], fP[NB];
    #pragma unroll
    for (int j = 0; j < NB; ++j) {
        fM[j] = load_rawF(cs - 1, y0, tid, fb[j]);
        fC[j] = load_rawF(cs,     y0, tid, fb[j]);
        fP[j] = load_rawF(cs + 1, y0, tid, fb[j]);
    }
    Halo hM = make_halo(sM, tid);
    Halo hC = make_halo(sC, tid);
    Row m[NB], c[NB];
    #pragma unroll
    for (int j = 0; j < NB; ++j) {
        m[j] = convert(sM, hM, fM[j], tid);
        c[j] = convert(sC, hC, fC[j], tid);
    }

    for (int x = cs; x <= ce; ++x) {
        const int xn = (x + 2 < NX) ? x + 2 : NX - 1;
        RawS sN = load_rawS(xn, y0, tid, A0, A1, B0, B1, B2);   // prefetch
        RawF fN[NB];
        #pragma unroll
        for (int j = 0; j < NB; ++j) fN[j] = load_rawF(xn, y0, tid, fb[j]);

        Halo hP = make_halo(sP, tid);
        #pragma unroll
        for (int j = 0; j < NB; ++j) {
            Row p = convert(sP, hP, fP[j], tid);
            v4f o;
            #pragma unroll
            for (int i = 0; i < 4; ++i) {
                const float dxP   = 0.5f * (p.pa[i] - m[j].pa[i]);
                const float dxxR  = p.rr[i] - 2.0f * c[j].rr[i] + m[j].rr[i];
                const float dxdyT = 0.5f * (p.tt[i] - m[j].tt[i]);
                const float df = -dxP + c[j].yc[i] + 0.5f * dxxR + dxdyT;
                o[i] = fmaxf(c[j].fc[i] + df * dtb[j], 0.0f);
            }
            __builtin_nontemporal_store(o, (v4f*)(ob[j] + x * NY + y0));
            m[j] = c[j]; c[j] = p;
        }
        sP = sN;
        #pragma unroll
        for (int j = 0; j < NB; ++j) fP[j] = fN[j];
    }

    // x = 0 one-sided (first chunk only; block-uniform branch)
    if (x0 == 0) {
        RawS s0 = load_rawS(0, y0, tid, A0, A1, B0, B1, B2);
        RawS s1 = load_rawS(1, y0, tid, A0, A1, B0, B1, B2);
        RawS s2 = load_rawS(2, y0, tid, A0, A1, B0, B1, B2);
        RawS s3 = load_rawS(3, y0, tid, A0, A1, B0, B1, B2);
        Halo h0 = make_halo(s0, tid), h1 = make_halo(s1, tid);
        Halo h2 = make_halo(s2, tid), h3 = make_halo(s3, tid);
        #pragma unroll
        for (int j = 0; j < NB; ++j) {
            Row r0 = convert(s0, h0, load_rawF(0, y0, tid, fb[j]), tid);
            Row r1 = convert(s1, h1, load_rawF(1, y0, tid, fb[j]), tid);
            Row r2 = convert(s2, h2, load_rawF(2, y0, tid, fb[j]), tid);
            Row r3 = convert(s3, h3, load_rawF(3, y0, tid, fb[j]), tid);
            v4f o;
            #pragma unroll
            for (int i = 0; i < 4; ++i) {
                const float dxP   = 0.5f * (-3.0f * r0.pa[i] + 4.0f * r1.pa[i] - r2.pa[i]);
                const float dxxR  = 2.0f * r0.rr[i] - 5.0f * r1.rr[i] + 4.0f * r2.rr[i] - r3.rr[i];
                const float dxdyT = 0.5f * (-3.0f * r0.tt[i] + 4.0f * r1.tt[i] - r2.tt[i]);
                const float df = -dxP + r0.yc[i] + 0.5f * dxxR + dxdyT;
                o[i] = fmaxf(r0.fc[i] + df * dtb[j], 0.0f);
            }
            __builtin_nontemporal_store(o, (v4f*)(ob[j] + y0));
        }
    }

    // x = NX-1 one-sided (last chunk only)
    if (x0 + CHUNK == NX) {
        RawS s0 = load_rawS(NX - 1, y0, tid, A0, A1, B0, B1, B2);
        RawS s1 = load_rawS(NX - 2, y0, tid, A0, A1, B0, B1, B2);
        RawS s2 = load_rawS(NX - 3, y0, tid, A0, A1, B0, B1, B2);
        RawS s3 = load_rawS(NX - 4, y0, tid, A0, A1, B0, B1, B2);
        Halo h0 = make_halo(s0, tid), h1 = make_halo(s1, tid);
        Halo h2 = make_halo(s2, tid), h3 = make_halo(s3, tid);
        #pragma unroll
        for (int j = 0; j < NB; ++j) {
            Row r0 = convert(s0, h0, load_rawF(NX - 1, y0, tid, fb[j]), tid);
            Row r1 = convert(s1, h1, load_rawF(NX - 2, y0, tid, fb[j]), tid);
            Row r2 = convert(s2, h2, load_rawF(NX - 3, y0, tid, fb[j]), tid);
            Row r3 = convert(s3, h3, load_rawF(NX - 4, y0, tid, fb[j]), tid);
            v4f o;
            #pragma unroll
            for (int i = 0; i < 4; ++i) {
                const float dxP   = 0.5f * (3.0f * r0.pa[i] - 4.0f * r1.pa[i] + r2.pa[i]);
                const float dxxR  = 2.0f * r0.rr[i] - 5.0f * r1.rr[i] + 4.0f * r2.rr[i] - r3.rr[i];
                const float dxdyT = 0.5f * (3.0f * r0.tt[i] - 4.0f * r1.tt[i] + r2.tt[i]);
                const float df = -dxP + r0.yc[i] + 0.5f * dxxR + dxdyT;
                o[i] = fmaxf(r0.fc[i] + df * dtb[j], 0.0f);
            }
            __builtin_nontemporal_store(o, (v4f*)(ob[j] + (NX - 1) * NY + y0));
        }
    }
}

extern "C" void kernel_launch(void* const* d_in, const int* in_sizes, int n_in,
                              void* d_out, int out_size, void* d_ws, size_t ws_size,
                              hipStream_t stream) {
    const float* f  = (const float*)d_in[0];
    const float* Ag = (const float*)d_in[1];
    const float* Bg = (const float*)d_in[2];
    const float* dt = (const float*)d_in[3];
    float* out = (float*)d_out;

    dim3 block(256, 1, 1);
    dim3 grid(NX / CHUNK, BATCH / NB, 1);
    fp2d_kernel<<<grid, block, 0, stream>>>(f, Ag, Bg, dt, out);
}